// Round 14
// baseline (531.540 us; speedup 1.0000x reference)
//
#include <hip/hip_runtime.h>
#include <stdint.h>

typedef __attribute__((ext_vector_type(8))) short s16x8;
typedef __attribute__((ext_vector_type(4))) float f32x4;

#define DM 1024
#define TOK 512
#define LDK 3072

static __device__ __forceinline__ float bf2f(short u) {
  union { unsigned int i; float f; } x;
  x.i = ((unsigned int)(unsigned short)u) << 16;
  return x.f;
}
static __device__ __forceinline__ short f2bf(float f) {
  union { float f; unsigned int i; } x; x.f = f;
  unsigned int r = x.i + 0x7FFFu + ((x.i >> 16) & 1u);
  return (short)(r >> 16);
}
static __device__ __forceinline__ f32x4 fzero4() {
  f32x4 z; z[0]=0.f; z[1]=0.f; z[2]=0.f; z[3]=0.f; return z;
}
static __device__ __forceinline__ s16x8 szero8() {
  s16x8 z; z[0]=0; z[1]=0; z[2]=0; z[3]=0; z[4]=0; z[5]=0; z[6]=0; z[7]=0; return z;
}
static __device__ __forceinline__ void gl_lds16(const short* g, short* s) {
  __builtin_amdgcn_global_load_lds((const __attribute__((address_space(1))) void*)g,
                                   (__attribute__((address_space(3))) void*)s, 16, 0, 0);
}

#define MFMA(a, b, c) __builtin_amdgcn_mfma_f32_16x16x32_bf16(a, b, c, 0, 0, 0)

// ---------------- cast relu(x) f32 -> bf16, 3 tensors ----------------
struct CastArgs { const float* x[3]; short* xb[3]; };
__global__ __launch_bounds__(256) void cast_relu_kernel(CastArgs a) {
  const float* x = a.x[blockIdx.y];
  short* xb = a.xb[blockIdx.y];
  size_t i = ((size_t)blockIdx.x * 256 + threadIdx.x) * 8;
  float4 v0 = *(const float4*)(x + i);
  float4 v1 = *(const float4*)(x + i + 4);
  s16x8 o;
  o[0] = f2bf(fmaxf(v0.x, 0.f)); o[1] = f2bf(fmaxf(v0.y, 0.f));
  o[2] = f2bf(fmaxf(v0.z, 0.f)); o[3] = f2bf(fmaxf(v0.w, 0.f));
  o[4] = f2bf(fmaxf(v1.x, 0.f)); o[5] = f2bf(fmaxf(v1.y, 0.f));
  o[6] = f2bf(fmaxf(v1.z, 0.f)); o[7] = f2bf(fmaxf(v1.w, 0.f));
  *(s16x8*)(xb + i) = o;
}

// ---------------- masked means: 4 row-groups x 256 d per block ----------------
__global__ __launch_bounds__(1024) void mean_kernel(const float* __restrict__ v,
                                                    const float* __restrict__ q,
                                                    const float* __restrict__ vmask,
                                                    const float* __restrict__ qmask,
                                                    float* __restrict__ vmean,
                                                    float* __restrict__ qmean) {
  __shared__ float part[4][256];
  __shared__ float msh[4];
  int dl = threadIdx.x & 255;
  int rg = threadIdx.x >> 8;
  int d = blockIdx.x * 256 + dl;
  int b = blockIdx.y;
  const float* x; const float* mk; float* out;
  if (blockIdx.z == 0) { x = v; mk = vmask; out = vmean; }
  else                 { x = q; mk = qmask; out = qmean; }
  const float* xp = x + ((size_t)b * TOK) * DM + d;
  const float* mp = mk + b * TOK;
  float s = 0.f, ms = 0.f;
  int r0 = rg * 128;
#pragma unroll 4
  for (int r = 0; r < 128; ++r) {
    float m = mp[r0 + r];
    ms += m;
    s += xp[(size_t)(r0 + r) * DM] * m;
  }
  part[rg][dl] = s;
  if (dl == 0) msh[rg] = ms;
  __syncthreads();
  if (rg == 0) {
    float st = part[0][dl] + part[1][dl] + part[2][dl] + part[3][dl];
    float mst = msh[0] + msh[1] + msh[2] + msh[3];
    out[b * DM + d] = st / mst;
  }
}

// ---------------- transpose + cast weights ----------------
struct TransArgs { const float* w[3]; short* wt[3]; };
__global__ void transpose_cast_kernel(TransArgs a, int K, int N) {
  __shared__ float tile[32][33];
  const float* w = a.w[blockIdx.z];
  short* wt = a.wt[blockIdx.z];
  int n0 = blockIdx.x * 32, k0 = blockIdx.y * 32;
  int tx = threadIdx.x, ty = threadIdx.y;
#pragma unroll
  for (int i = 0; i < 32; i += 8)
    tile[ty + i][tx] = w[(size_t)(k0 + ty + i) * N + n0 + tx];
  __syncthreads();
#pragma unroll
  for (int i = 0; i < 32; i += 8)
    wt[(size_t)(n0 + ty + i) * K + k0 + tx] = f2bf(tile[tx][ty + i]);
}

// ---------------- gates: 4 k-groups x 256 n per block ----------------
__global__ __launch_bounds__(1024) void gate_kernel(const float* __restrict__ vmean,
                                                    const float* __restrict__ qmean,
                                                    const float* __restrict__ v4q_w,
                                                    const float* __restrict__ v4q_b,
                                                    const float* __restrict__ q4v_w,
                                                    const float* __restrict__ q4v_b,
                                                    float* __restrict__ gate_q,
                                                    float* __restrict__ gate_v) {
  __shared__ float part[4][256];
  int nl = threadIdx.x & 255;
  int kg = threadIdx.x >> 8;
  int n = blockIdx.x * 256 + nl;
  int b = blockIdx.y;
  const float* mean; const float* w; const float* bias; float* out;
  if (blockIdx.z == 0) { mean = vmean; w = v4q_w; bias = v4q_b; out = gate_q; }
  else                 { mean = qmean; w = q4v_w; bias = q4v_b; out = gate_v; }
  const float* mp = mean + b * DM;
  float acc = 0.f;
  int k0 = kg * 256;
#pragma unroll 4
  for (int k = 0; k < 256; ++k) {
    float mv = mp[k0 + k];
    mv = mv > 0.f ? mv : 0.f;
    acc += mv * w[(size_t)(k0 + k) * DM + n];
  }
  part[kg][nl] = acc;
  __syncthreads();
  if (kg == 0) {
    float a = part[0][nl] + part[1][nl] + part[2][nl] + part[3][nl] + bias[n];
    out[b * DM + n] = 1.f + 1.f / (1.f + __expf(-a));
  }
}

// ---------------- memory-token K rows ----------------
__global__ void kmem_kernel(const float* __restrict__ m_v_k, const float* __restrict__ m_c_k,
                            const float* __restrict__ gate_v,
                            float* __restrict__ kmem_v, float* __restrict__ kmem_c) {
  int d = threadIdx.x;
  int b = blockIdx.x;
  if (b < 16) kmem_v[b * DM + d] = 32.0f * m_v_k[d] * gate_v[b * DM + d];
  else        kmem_c[d] = 32.0f * m_c_k[d];
}

// ---------------- valid-row compaction ----------------
struct CompArgs { const float* mask[3]; int* idx; int* nv; };
__global__ __launch_bounds__(64) void compact_kernel(CompArgs a) {
  int b = blockIdx.x, mod = blockIdx.y;
  const float* mk = a.mask[mod] + b * TOK;
  int* idx = a.idx + (mod * 16 + b) * TOK;
  int l = threadIdx.x;
  int base = 0;
#pragma unroll 1
  for (int ch = 0; ch < 8; ++ch) {
    int pos = ch * 64 + l;
    bool valid = mk[pos] != 0.f;
    unsigned long long bal = __ballot(valid);
    int pre = __popcll(bal & ((1ull << l) - 1ull));
    if (valid) idx[base + pre] = pos;
    base += __popcll(bal);
  }
  if (l == 0) a.nv[mod * 16 + b] = base;
}

// ---------------- GEMM: 128x256 tile, 512 threads, wave tile 64x64 ----------------
// LDS traffic 0.5 KB/MFMA (vs 1.0 for 64x32 wave tiles) -- LDS-BW-bound fix.
// 48KB LDS -> 3 blocks/CU = 24 waves. M-granularity stays 128 for compaction.
struct GemmArgs {
  const short* A[3]; const short* BT[3];
  const float* bias[3]; const float* gate[3];
  short* outB[3]; float* outF[3];
  const int* idx;   // [3][16][512] or null
  const int* nv;    // [3][16] or null
};
__global__ __launch_bounds__(512) void gemm_kernel(GemmArgs ga, int N, int K) {
  __shared__ short As[128 * 64];   // 16KB
  __shared__ short Bs[256 * 64];   // 32KB
  int z = blockIdx.z;
  const short* A = ga.A[z];
  const short* BT = ga.BT[z];
  const float* bias = ga.bias[z];
  const float* gate = ga.gate[z];
  short* outB = ga.outB[z];
  float* outF = ga.outF[z];

  int bx = blockIdx.x;
  int b = bx >> 2, m0c = (bx & 3) * 128;
  int nvb = TOK;
  const int* idxb = nullptr;
  if (ga.nv != nullptr) {
    nvb = ga.nv[z * 16 + b];
    if (m0c >= nvb) return;          // whole-block exit before any barrier
    idxb = ga.idx + (z * 16 + b) * TOK;
  }
  int n0 = blockIdx.y * 256;
  int tid = threadIdx.x;
  int w = tid >> 6, l = tid & 63;
  int wr = w >> 2, wc = w & 3;       // 2x4 wave grid; wave tile 64 rows x 64 cols
  int lg = l >> 4, lo = l & 15;

  int cc = (l & 7) ^ (l >> 3);       // proven staging involution
  const short* pa[2];
#pragma unroll
  for (int i = 0; i < 2; ++i) {
    int row = (w * 2 + i) * 8 + (l >> 3);     // 0..127
    int rg = m0c + row;
    if (idxb != nullptr) rg = idxb[(m0c + row < nvb) ? (m0c + row) : 0];
    pa[i] = A + ((size_t)b * TOK + rg) * K + cc * 8;
  }
  const short* pb[4];
#pragma unroll
  for (int i = 0; i < 4; ++i) {
    int row = (w * 4 + i) * 8 + (l >> 3);     // 0..255
    pb[i] = BT + (size_t)(n0 + row) * K + cc * 8;
  }

  f32x4 acc[4][4];
#pragma unroll
  for (int i = 0; i < 4; ++i)
#pragma unroll
    for (int j = 0; j < 4; ++j) acc[i][j] = fzero4();

  for (int k0 = 0; k0 < K; k0 += 64) {
#pragma unroll
    for (int i = 0; i < 2; ++i)
      gl_lds16(pa[i] + k0, As + (w * 2 + i) * 512);
#pragma unroll
    for (int i = 0; i < 4; ++i)
      gl_lds16(pb[i] + k0, Bs + (w * 4 + i) * 512);
    __syncthreads();
#pragma unroll
    for (int ks = 0; ks < 2; ++ks) {
      int lc = ks * 4 + lg;
      s16x8 af[4], bfr[4];
#pragma unroll
      for (int i = 0; i < 4; ++i) {
        int ar = wr * 64 + i * 16 + lo;                    // 0..127
        af[i] = *(const s16x8*)(As + ar * 64 + ((lc ^ (ar & 7)) * 8));
      }
#pragma unroll
      for (int j = 0; j < 4; ++j) {
        int br = wc * 64 + j * 16 + lo;                    // 0..255
        bfr[j] = *(const s16x8*)(Bs + br * 64 + ((lc ^ (br & 7)) * 8));
      }
#pragma unroll
      for (int i = 0; i < 4; ++i)
#pragma unroll
        for (int j = 0; j < 4; ++j)
          acc[i][j] = MFMA(af[i], bfr[j], acc[i][j]);
    }
    __syncthreads();
  }

#pragma unroll
  for (int i = 0; i < 4; ++i)
#pragma unroll
    for (int j = 0; j < 4; ++j) {
      int rowc = m0c + wr * 64 + i * 16 + (lg << 2);
      int col = n0 + wc * 64 + j * 16 + lo;
      float cs = 1.f;
      if (gate != nullptr && col < 2048) cs = gate[b * DM + (col & 1023)];
      float bv = bias[col];
#pragma unroll
      for (int r = 0; r < 4; ++r) {
        if (rowc + r >= nvb) continue;
        float val = (acc[i][j][r] + bv) * cs;
        size_t orow = (size_t)b * TOK + rowc + r;
        if (outB != nullptr) outB[orow * N + col] = f2bf(val);
        else                 outF[orow * N + col] = val;
      }
    }
}

// ---------------- fused flash attention on compacted K/V/Q ----------------
struct AttnArgs {
  const short* kqv[3];
  const float* kmem[3];
  const float* vmem[3];
  const float* xin[3];
  short* xu[3];
  const int* idx;
  const int* nv;
  int kmem_bstride[3];
};

__global__ __launch_bounds__(512) void attn_kernel(AttnArgs args) {
  __shared__ short Ks[64 * 128];
  __shared__ short Vs[8 * 1032];
  __shared__ short Ps[8 * 1216];
  int bid = blockIdx.x;
  int mod = bid >> 9;
  int r9 = bid & 511;
  int x = r9 & 7, jj = r9 >> 3;
  int p = x * 16 + (jj & 15), qt = jj >> 4;
  int b = p >> 3, h = p & 7;

  int nvb = args.nv[mod * 16 + b];
  if (qt * 128 >= nvb) return;

  const short* kqv  = args.kqv[mod];
  const float* kmem = args.kmem[mod];
  const float* vmem = args.vmem[mod];
  const float* xin  = args.xin[mod];
  short* xu = args.xu[mod];
  const int* idxb = args.idx + (mod * 16 + b) * TOK;
  int kmem_bs = args.kmem_bstride[mod];

  int tid = threadIdx.x;
  int w = tid >> 6, l = tid & 63;
  int lg = l >> 4, lo = l & 15;
  size_t rowbase = (size_t)b * TOK;
  int q0 = qt * 128 + w * 16;
  const float scale = 0.08838834764831845f;
  short* Pw = Ps + w * 1216;
  int nkt = (nvb + 63) >> 6;

  s16x8 ones;
#pragma unroll
  for (int j = 0; j < 8; ++j) ones[j] = (short)0x3F80;

  int qrow = q0 + lo;
  s16x8 qf[4];
#pragma unroll
  for (int c = 0; c < 4; ++c)
    qf[c] = (qrow < nvb)
      ? *(const s16x8*)(kqv + (rowbase + qrow) * LDK + 1024 + h * 128 + c * 32 + lg * 8)
      : szero8();

  float m;
  f32x4 oacc[9];
#pragma unroll
  for (int c = 0; c < 9; ++c) oacc[c] = fzero4();

  if (kmem != nullptr) {
    const float* km = kmem + (size_t)b * kmem_bs + h * 128;
    float part = 0.f;
#pragma unroll
    for (int c = 0; c < 4; ++c)
#pragma unroll
      for (int j = 0; j < 8; ++j)
        part += bf2f(qf[c][j]) * km[c * 32 + lg * 8 + j];
    part += __shfl_xor(part, 16);
    part += __shfl_xor(part, 32);
    float sm = part * scale;
    float sm4[4], w4[4];
#pragma unroll
    for (int r = 0; r < 4; ++r) sm4[r] = __shfl(sm, lg * 4 + r);
    m = fmaxf(fmaxf(sm4[0], sm4[1]), fmaxf(sm4[2], sm4[3]));
#pragma unroll
    for (int r = 0; r < 4; ++r) w4[r] = __expf(sm4[r] - m);
#pragma unroll
    for (int c = 0; c < 8; ++c) {
      float vv = vmem[h * 128 + c * 16 + lo];
#pragma unroll
      for (int r = 0; r < 4; ++r) oacc[c][r] = w4[r] * vv;
    }
#pragma unroll
    for (int r = 0; r < 4; ++r) oacc[8][r] = w4[r];
  } else {
    m = -3.0e38f;
  }

  int c8A = 2 * w, c8B = 2 * w + 1;
  s16x8 vregA = (l < nvb)
    ? *(const s16x8*)(kqv + (rowbase + l) * LDK + 2048 + h * 128 + c8A * 8) : szero8();
  s16x8 vregB = (l < nvb)
    ? *(const s16x8*)(kqv + (rowbase + l) * LDK + 2048 + h * 128 + c8B * 8) : szero8();

#pragma unroll 1
  for (int kt = 0; kt < nkt; ++kt) {
    __syncthreads();
#pragma unroll
    for (int i = 0; i < 2; ++i) {
      int inst = w * 2 + i;
      int row = inst * 4 + lg;
      int csrc = (l & 15) ^ (row & 7);
      gl_lds16(kqv + (rowbase + kt * 64 + row) * LDK + h * 128 + csrc * 8,
               Ks + inst * 512);
    }
    {
      short* baseA = Vs + (l >> 3) * 1032 + c8A * 64 + (l & 7);
      short* baseB = Vs + (l >> 3) * 1032 + c8B * 64 + (l & 7);
#pragma unroll
      for (int j = 0; j < 8; ++j) baseA[j * 8] = vregA[j];
#pragma unroll
      for (int j = 0; j < 8; ++j) baseB[j * 8] = vregB[j];
    }
    __syncthreads();

    if (kt + 1 < nkt) {
      int row2 = (kt + 1) * 64 + l;
      vregA = (row2 < nvb)
        ? *(const s16x8*)(kqv + (rowbase + row2) * LDK + 2048 + h * 128 + c8A * 8) : szero8();
      vregB = (row2 < nvb)
        ? *(const s16x8*)(kqv + (rowbase + row2) * LDK + 2048 + h * 128 + c8B * 8) : szero8();
    }

    f32x4 s4[4];
#pragma unroll
    for (int sub = 0; sub < 4; ++sub) {
      f32x4 acc = fzero4();
      int krow = sub * 16 + lo;
#pragma unroll
      for (int cc = 0; cc < 4; ++cc) {
        s16x8 kf = *(const s16x8*)(Ks + krow * 128 + (((cc * 4 + lg) ^ (lo & 7)) * 8));
        acc = MFMA(qf[cc], kf, acc);
      }
      s4[sub] = acc;
    }

    int pos0 = kt * 64 + lo;
    float a[4][4];
    float pmax = -3.0e38f;
#pragma unroll
    for (int r = 0; r < 4; ++r) {
      a[0][r] = (pos0      < nvb) ? s4[0][r] * scale : -1e9f;
      a[1][r] = (pos0 + 16 < nvb) ? s4[1][r] * scale : -1e9f;
      a[2][r] = (pos0 + 32 < nvb) ? s4[2][r] * scale : -1e9f;
      a[3][r] = (pos0 + 48 < nvb) ? s4[3][r] * scale : -1e9f;
      pmax = fmaxf(pmax, fmaxf(fmaxf(a[0][r], a[1][r]), fmaxf(a[2][r], a[3][r])));
    }
    pmax = fmaxf(pmax, __shfl_xor(pmax, 1));
    pmax = fmaxf(pmax, __shfl_xor(pmax, 2));
    pmax = fmaxf(pmax, __shfl_xor(pmax, 4));
    pmax = fmaxf(pmax, __shfl_xor(pmax, 8));
    if (!__all(pmax - m <= 8.0f)) {
      float nm = fmaxf(m, pmax);
      float f = __expf(m - nm);
#pragma unroll
      for (int c = 0; c < 9; ++c)
#pragma unroll
        for (int r = 0; r < 4; ++r) oacc[c][r] *= f;
      m = nm;
    }

#pragma unroll
    for (int sub = 0; sub < 4; ++sub)
#pragma unroll
      for (int r = 0; r < 4; ++r)
        Pw[(lg * 4 + r) * 76 + sub * 16 + lo] = f2bf(__expf(a[sub][r] - m));

    s16x8 pf0 = *(const s16x8*)(Pw + lo * 76 + lg * 8);
    s16x8 pf1 = *(const s16x8*)(Pw + lo * 76 + 32 + lg * 8);
#pragma unroll
    for (int c = 0; c < 8; ++c) {
      s16x8 vf0 = *(const s16x8*)(Vs + lg * 1032 + (c * 16 + lo) * 8);
      s16x8 vf1 = *(const s16x8*)(Vs + (4 + lg) * 1032 + (c * 16 + lo) * 8);
      oacc[c] = MFMA(pf0, vf0, oacc[c]);
      oacc[c] = MFMA(pf1, vf1, oacc[c]);
    }
    oacc[8] = MFMA(pf0, ones, oacc[8]);
    oacc[8] = MFMA(pf1, ones, oacc[8]);
  }

  int orig[4];
#pragma unroll
  for (int r = 0; r < 4; ++r) {
    int crow = q0 + lg * 4 + r;
    orig[r] = (crow < nvb) ? idxb[crow] : -1;
  }
  float invl[4];
#pragma unroll
  for (int r = 0; r < 4; ++r) invl[r] = 1.f / oacc[8][r];
#pragma unroll
  for (int c = 0; c < 8; ++c)
#pragma unroll
    for (int r = 0; r < 4; ++r) {
      if (orig[r] < 0) continue;
      size_t row = rowbase + orig[r];
      int col = h * 128 + c * 16 + lo;
      float val = oacc[c][r] * invl[r] + xin[row * DM + col];
      xu[row * DM + col] = f2bf(val);
    }
}

// ---------------- masked rows: xu = x + uniform avg of valid V (+mem) ----------------
struct UniArgs {
  const short* kqv[3]; const float* mask[3]; const float* mem[3];
  const float* xin[3]; short* xu[3]; const int* nv;
};
__global__ __launch_bounds__(1024) void uniform_fill_kernel(UniArgs a) {
  __shared__ float part[8][1024];
  int b = blockIdx.x, mod = blockIdx.y;
  int nvb = a.nv[mod * 16 + b];
  const short* kv = a.kqv[mod];
  int tid = threadIdx.x;
  int g = tid >> 7;
  int dd = tid & 127;

  f32x4 p0 = fzero4(), p1 = fzero4();
#pragma unroll 2
  for (int r = g; r < nvb; r += 8) {
    s16x8 vv = *(const s16x8*)(kv + ((size_t)b * TOK + r) * LDK + 2048 + dd * 8);
#pragma unroll
    for (int j = 0; j < 4; ++j) { p0[j] += bf2f(vv[j]); p1[j] += bf2f(vv[4 + j]); }
  }
  *(f32x4*)&part[g][dd * 8] = p0;
  *(f32x4*)&part[g][dd * 8 + 4] = p1;
  __syncthreads();
  {
    float s = 0.f;
#pragma unroll
    for (int gg = 0; gg < 8; ++gg) s += part[gg][tid];
    float denom = (float)nvb;
    if (a.mem[mod] != nullptr) { s += a.mem[mod][tid]; denom += 1.f; }
    __syncthreads();
    part[0][tid] = s / denom;
  }
  __syncthreads();
  float avg[8];
#pragma unroll
  for (int j = 0; j < 8; ++j) avg[j] = part[0][dd * 8 + j];

  const float* mk = a.mask[mod] + b * TOK;
  const float* x = a.xin[mod];
  short* xu = a.xu[mod];
#pragma unroll 1
  for (int rb = 0; rb < TOK; rb += 8) {
    int r = rb + g;
    if (mk[r] != 0.f) continue;
    size_t base = ((size_t)b * TOK + r) * DM + dd * 8;
    float4 x0 = *(const float4*)(x + base);
    float4 x1 = *(const float4*)(x + base + 4);
    s16x8 o;
    o[0] = f2bf(x0.x + avg[0]); o[1] = f2bf(x0.y + avg[1]);
    o[2] = f2bf(x0.z + avg[2]); o[3] = f2bf(x0.w + avg[3]);
    o[4] = f2bf(x1.x + avg[4]); o[5] = f2bf(x1.y + avg[5]);
    o[6] = f2bf(x1.z + avg[6]); o[7] = f2bf(x1.w + avg[7]);
    *(s16x8*)(xu + base) = o;
  }
}

// ---------------- launcher ----------------
extern "C" void kernel_launch(void* const* d_in, const int* in_sizes, int n_in,
                              void* d_out, int out_size, void* d_ws, size_t ws_size,
                              hipStream_t stream) {
  const float* v      = (const float*)d_in[0];
  const float* q      = (const float*)d_in[1];
  const float* c      = (const float*)d_in[2];
  const float* v_mask = (const float*)d_in[3];
  const float* q_mask = (const float*)d_in[4];
  const float* c_mask = (const float*)d_in[5];
  const float* v4q_w  = (const float*)d_in[6];
  const float* v4q_b  = (const float*)d_in[7];
  const float* q4v_w  = (const float*)d_in[8];
  const float* q4v_b  = (const float*)d_in[9];
  const float* v_lin_w = (const float*)d_in[10];
  const float* v_lin_b = (const float*)d_in[11];
  const float* q_lin_w = (const float*)d_in[12];
  const float* q_lin_b = (const float*)d_in[13];
  const float* c_lin_w = (const float*)d_in[14];
  const float* c_lin_b = (const float*)d_in[15];
  const float* m_v_k  = (const float*)d_in[16];
  const float* m_v_v  = (const float*)d_in[17];
  const float* m_c_k  = (const float*)d_in[18];
  const float* m_c_v  = (const float*)d_in[19];
  const float* v_out_w = (const float*)d_in[20];
  const float* v_out_b = (const float*)d_in[21];
  const float* q_out_w = (const float*)d_in[22];
  const float* q_out_b = (const float*)d_in[23];
  const float* c_out_w = (const float*)d_in[24];
  const float* c_out_b = (const float*)d_in[25];

  const size_t MB = 1024ull * 1024ull;
  char* ws = (char*)d_ws;
  short* xbf_v = (short*)(ws + 0 * MB);      // 16MB each; reused as xu after trans GEMMs
  short* xbf_q = (short*)(ws + 16 * MB);
  short* xbf_c = (short*)(ws + 32 * MB);
  short* wt_lin_v = (short*)(ws + 48 * MB);
  short* wt_lin_q = (short*)(ws + 54 * MB);
  short* wt_lin_c = (short*)(ws + 60 * MB);
  short* wt_out_v = (short*)(ws + 66 * MB);
  short* wt_out_q = (short*)(ws + 68 * MB);
  short* wt_out_c = (short*)(ws + 70 * MB);
  short* kqv_v = (short*)(ws + 72 * MB);     // 48MB each
  short* kqv_q = (short*)(ws + 120 * MB);
  short* kqv_c = (short*)(ws + 168 * MB);
  float* vmean  = (float*)(ws + 216 * MB);
  float* qmean  = vmean + 16 * 1024;
  float* gate_q = qmean + 16 * 1024;
  float* gate_v = gate_q + 16 * 1024;
  float* kmem_v = gate_v + 16 * 1024;
  float* kmem_c = kmem_v + 16 * 1024;
  int* idxbuf = (int*)(ws + 217 * MB);
  int* nvbuf  = (int*)(ws + 218 * MB);

  CastArgs ca;
  ca.x[0] = v; ca.x[1] = q; ca.x[2] = c;
  ca.xb[0] = xbf_v; ca.xb[1] = xbf_q; ca.xb[2] = xbf_c;
  cast_relu_kernel<<<dim3(4096, 3), 256, 0, stream>>>(ca);
  mean_kernel<<<dim3(4, 16, 2), 1024, 0, stream>>>(v, q, v_mask, q_mask, vmean, qmean);

  TransArgs tl;
  tl.w[0] = v_lin_w; tl.w[1] = q_lin_w; tl.w[2] = c_lin_w;
  tl.wt[0] = wt_lin_v; tl.wt[1] = wt_lin_q; tl.wt[2] = wt_lin_c;
  transpose_cast_kernel<<<dim3(96, 32, 3), dim3(32, 8), 0, stream>>>(tl, 1024, 3072);
  TransArgs to;
  to.w[0] = v_out_w; to.w[1] = q_out_w; to.w[2] = c_out_w;
  to.wt[0] = wt_out_v; to.wt[1] = wt_out_q; to.wt[2] = wt_out_c;
  transpose_cast_kernel<<<dim3(32, 32, 3), dim3(32, 8), 0, stream>>>(to, 1024, 1024);

  gate_kernel<<<dim3(4, 16, 2), 1024, 0, stream>>>(vmean, qmean, v4q_w, v4q_b, q4v_w, q4v_b,
                                                   gate_q, gate_v);
  kmem_kernel<<<17, 1024, 0, stream>>>(m_v_k, m_c_k, gate_v, kmem_v, kmem_c);

  CompArgs cpa;
  cpa.mask[0] = v_mask; cpa.mask[1] = q_mask; cpa.mask[2] = c_mask;
  cpa.idx = idxbuf; cpa.nv = nvbuf;
  compact_kernel<<<dim3(16, 3), 64, 0, stream>>>(cpa);

  GemmArgs gt;
  gt.A[0] = xbf_v; gt.A[1] = xbf_q; gt.A[2] = xbf_c;
  gt.BT[0] = wt_lin_v; gt.BT[1] = wt_lin_q; gt.BT[2] = wt_lin_c;
  gt.bias[0] = v_lin_b; gt.bias[1] = q_lin_b; gt.bias[2] = c_lin_b;
  gt.gate[0] = gate_v; gt.gate[1] = gate_q; gt.gate[2] = nullptr;
  gt.outB[0] = kqv_v; gt.outB[1] = kqv_q; gt.outB[2] = kqv_c;
  gt.outF[0] = nullptr; gt.outF[1] = nullptr; gt.outF[2] = nullptr;
  gt.idx = idxbuf; gt.nv = nvbuf;
  gemm_kernel<<<dim3(64, 12, 3), 512, 0, stream>>>(gt, 3072, 1024);

  AttnArgs aa;
  aa.kqv[0] = kqv_v; aa.kqv[1] = kqv_q; aa.kqv[2] = kqv_c;
  aa.kmem[0] = kmem_v; aa.kmem[1] = nullptr; aa.kmem[2] = kmem_c;
  aa.vmem[0] = m_v_v; aa.vmem[1] = nullptr; aa.vmem[2] = m_c_v;
  aa.xin[0] = v; aa.xin[1] = q; aa.xin[2] = c;
  aa.xu[0] = xbf_v; aa.xu[1] = xbf_q; aa.xu[2] = xbf_c;
  aa.idx = idxbuf; aa.nv = nvbuf;
  aa.kmem_bstride[0] = 1024; aa.kmem_bstride[1] = 0; aa.kmem_bstride[2] = 0;
  attn_kernel<<<1536, 512, 0, stream>>>(aa);

  UniArgs ua;
  ua.kqv[0] = kqv_v; ua.kqv[1] = kqv_q; ua.kqv[2] = kqv_c;
  ua.mask[0] = v_mask; ua.mask[1] = q_mask; ua.mask[2] = c_mask;
  ua.mem[0] = m_v_v; ua.mem[1] = nullptr; ua.mem[2] = m_c_v;
  ua.xin[0] = v; ua.xin[1] = q; ua.xin[2] = c;
  ua.xu[0] = xbf_v; ua.xu[1] = xbf_q; ua.xu[2] = xbf_c;
  ua.nv = nvbuf;
  uniform_fill_kernel<<<dim3(16, 3), 1024, 0, stream>>>(ua);

  float* outp = (float*)d_out;
  GemmArgs go;
  go.A[0] = xbf_v; go.A[1] = xbf_q; go.A[2] = xbf_c;
  go.BT[0] = wt_out_v; go.BT[1] = wt_out_q; go.BT[2] = wt_out_c;
  go.bias[0] = v_out_b; go.bias[1] = q_out_b; go.bias[2] = c_out_b;
  go.gate[0] = nullptr; go.gate[1] = nullptr; go.gate[2] = nullptr;
  go.outB[0] = nullptr; go.outB[1] = nullptr; go.outB[2] = nullptr;
  go.outF[0] = outp; go.outF[1] = outp + 8388608; go.outF[2] = outp + 16777216;
  go.idx = nullptr; go.nv = nullptr;
  gemm_kernel<<<dim3(64, 4, 3), 512, 0, stream>>>(go, 1024, 1024);
}

// Round 15
// 508.641 us; speedup vs baseline: 1.0450x; 1.0450x over previous
//
#include <hip/hip_runtime.h>
#include <stdint.h>

typedef __attribute__((ext_vector_type(8))) short s16x8;
typedef __attribute__((ext_vector_type(4))) float f32x4;

#define DM 1024
#define TOK 512
#define LDK 3072

static __device__ __forceinline__ float bf2f(short u) {
  union { unsigned int i; float f; } x;
  x.i = ((unsigned int)(unsigned short)u) << 16;
  return x.f;
}
static __device__ __forceinline__ short f2bf(float f) {
  union { float f; unsigned int i; } x; x.f = f;
  unsigned int r = x.i + 0x7FFFu + ((x.i >> 16) & 1u);
  return (short)(r >> 16);
}
static __device__ __forceinline__ f32x4 fzero4() {
  f32x4 z; z[0]=0.f; z[1]=0.f; z[2]=0.f; z[3]=0.f; return z;
}
static __device__ __forceinline__ s16x8 szero8() {
  s16x8 z; z[0]=0; z[1]=0; z[2]=0; z[3]=0; z[4]=0; z[5]=0; z[6]=0; z[7]=0; return z;
}
static __device__ __forceinline__ void gl_lds16(const short* g, short* s) {
  __builtin_amdgcn_global_load_lds((const __attribute__((address_space(1))) void*)g,
                                   (__attribute__((address_space(3))) void*)s, 16, 0, 0);
}

#define MFMA(a, b, c) __builtin_amdgcn_mfma_f32_16x16x32_bf16(a, b, c, 0, 0, 0)

// ---------------- cast relu(x) f32 -> bf16, valid rows only ----------------
// block 256 = 2 rows x 128 col-octets; masked rows skipped (never read downstream:
// trans-GEMM gathers valid rows via idx; attn/uniform_fill overwrite xu before out-GEMM).
struct CastArgs { const float* x[3]; short* xb[3]; const float* mask[3]; };
__global__ __launch_bounds__(256) void cast_relu_kernel(CastArgs a) {
  const float* x = a.x[blockIdx.y];
  short* xb = a.xb[blockIdx.y];
  const float* mk = a.mask[blockIdx.y];
  int row = blockIdx.x * 2 + (threadIdx.x >> 7);
  if (mk[row] == 0.f) return;
  size_t i = (size_t)row * DM + (threadIdx.x & 127) * 8;
  float4 v0 = *(const float4*)(x + i);
  float4 v1 = *(const float4*)(x + i + 4);
  s16x8 o;
  o[0] = f2bf(fmaxf(v0.x, 0.f)); o[1] = f2bf(fmaxf(v0.y, 0.f));
  o[2] = f2bf(fmaxf(v0.z, 0.f)); o[3] = f2bf(fmaxf(v0.w, 0.f));
  o[4] = f2bf(fmaxf(v1.x, 0.f)); o[5] = f2bf(fmaxf(v1.y, 0.f));
  o[6] = f2bf(fmaxf(v1.z, 0.f)); o[7] = f2bf(fmaxf(v1.w, 0.f));
  *(s16x8*)(xb + i) = o;
}

// ---------------- masked means: 4 row-groups x 256 d per block ----------------
__global__ __launch_bounds__(1024) void mean_kernel(const float* __restrict__ v,
                                                    const float* __restrict__ q,
                                                    const float* __restrict__ vmask,
                                                    const float* __restrict__ qmask,
                                                    float* __restrict__ vmean,
                                                    float* __restrict__ qmean) {
  __shared__ float part[4][256];
  __shared__ float msh[4];
  int dl = threadIdx.x & 255;
  int rg = threadIdx.x >> 8;
  int d = blockIdx.x * 256 + dl;
  int b = blockIdx.y;
  const float* x; const float* mk; float* out;
  if (blockIdx.z == 0) { x = v; mk = vmask; out = vmean; }
  else                 { x = q; mk = qmask; out = qmean; }
  const float* xp = x + ((size_t)b * TOK) * DM + d;
  const float* mp = mk + b * TOK;
  float s = 0.f, ms = 0.f;
  int r0 = rg * 128;
#pragma unroll 4
  for (int r = 0; r < 128; ++r) {
    float m = mp[r0 + r];
    ms += m;
    s += xp[(size_t)(r0 + r) * DM] * m;
  }
  part[rg][dl] = s;
  if (dl == 0) msh[rg] = ms;
  __syncthreads();
  if (rg == 0) {
    float st = part[0][dl] + part[1][dl] + part[2][dl] + part[3][dl];
    float mst = msh[0] + msh[1] + msh[2] + msh[3];
    out[b * DM + d] = st / mst;
  }
}

// ---------------- transpose + cast weights ----------------
struct TransArgs { const float* w[3]; short* wt[3]; };
__global__ void transpose_cast_kernel(TransArgs a, int K, int N) {
  __shared__ float tile[32][33];
  const float* w = a.w[blockIdx.z];
  short* wt = a.wt[blockIdx.z];
  int n0 = blockIdx.x * 32, k0 = blockIdx.y * 32;
  int tx = threadIdx.x, ty = threadIdx.y;
#pragma unroll
  for (int i = 0; i < 32; i += 8)
    tile[ty + i][tx] = w[(size_t)(k0 + ty + i) * N + n0 + tx];
  __syncthreads();
#pragma unroll
  for (int i = 0; i < 32; i += 8)
    wt[(size_t)(n0 + ty + i) * K + k0 + tx] = f2bf(tile[tx][ty + i]);
}

// ---------------- gates: 4 k-groups x 256 n per block ----------------
__global__ __launch_bounds__(1024) void gate_kernel(const float* __restrict__ vmean,
                                                    const float* __restrict__ qmean,
                                                    const float* __restrict__ v4q_w,
                                                    const float* __restrict__ v4q_b,
                                                    const float* __restrict__ q4v_w,
                                                    const float* __restrict__ q4v_b,
                                                    float* __restrict__ gate_q,
                                                    float* __restrict__ gate_v) {
  __shared__ float part[4][256];
  int nl = threadIdx.x & 255;
  int kg = threadIdx.x >> 8;
  int n = blockIdx.x * 256 + nl;
  int b = blockIdx.y;
  const float* mean; const float* w; const float* bias; float* out;
  if (blockIdx.z == 0) { mean = vmean; w = v4q_w; bias = v4q_b; out = gate_q; }
  else                 { mean = qmean; w = q4v_w; bias = q4v_b; out = gate_v; }
  const float* mp = mean + b * DM;
  float acc = 0.f;
  int k0 = kg * 256;
#pragma unroll 4
  for (int k = 0; k < 256; ++k) {
    float mv = mp[k0 + k];
    mv = mv > 0.f ? mv : 0.f;
    acc += mv * w[(size_t)(k0 + k) * DM + n];
  }
  part[kg][nl] = acc;
  __syncthreads();
  if (kg == 0) {
    float a = part[0][nl] + part[1][nl] + part[2][nl] + part[3][nl] + bias[n];
    out[b * DM + n] = 1.f + 1.f / (1.f + __expf(-a));
  }
}

// ---------------- memory-token K rows ----------------
__global__ void kmem_kernel(const float* __restrict__ m_v_k, const float* __restrict__ m_c_k,
                            const float* __restrict__ gate_v,
                            float* __restrict__ kmem_v, float* __restrict__ kmem_c) {
  int d = threadIdx.x;
  int b = blockIdx.x;
  if (b < 16) kmem_v[b * DM + d] = 32.0f * m_v_k[d] * gate_v[b * DM + d];
  else        kmem_c[d] = 32.0f * m_c_k[d];
}

// ---------------- valid-row compaction ----------------
struct CompArgs { const float* mask[3]; int* idx; int* nv; };
__global__ __launch_bounds__(64) void compact_kernel(CompArgs a) {
  int b = blockIdx.x, mod = blockIdx.y;
  const float* mk = a.mask[mod] + b * TOK;
  int* idx = a.idx + (mod * 16 + b) * TOK;
  int l = threadIdx.x;
  int base = 0;
#pragma unroll 1
  for (int ch = 0; ch < 8; ++ch) {
    int pos = ch * 64 + l;
    bool valid = mk[pos] != 0.f;
    unsigned long long bal = __ballot(valid);
    int pre = __popcll(bal & ((1ull << l) - 1ull));
    if (valid) idx[base + pre] = pos;
    base += __popcll(bal);
  }
  if (l == 0) a.nv[mod * 16 + b] = base;
}

// ---------------- GEMM: 128x128 tile, 512 threads (8 waves), single-buffer ----------------
// Round-13 proven config: 32KB LDS + 8 waves -> 32 waves/CU.
struct GemmArgs {
  const short* A[3]; const short* BT[3];
  const float* bias[3]; const float* gate[3];
  short* outB[3]; float* outF[3];
  const int* idx;   // [3][16][512] or null
  const int* nv;    // [3][16] or null
};
__global__ __launch_bounds__(512) void gemm_kernel(GemmArgs ga, int N, int K) {
  __shared__ short As[128 * 64];   // 16KB
  __shared__ short Bs[128 * 64];   // 16KB
  int z = blockIdx.z;
  const short* A = ga.A[z];
  const short* BT = ga.BT[z];
  const float* bias = ga.bias[z];
  const float* gate = ga.gate[z];
  short* outB = ga.outB[z];
  float* outF = ga.outF[z];

  int bx = blockIdx.x;
  int b = bx >> 2, m0c = (bx & 3) * 128;
  int nvb = TOK;
  const int* idxb = nullptr;
  if (ga.nv != nullptr) {
    nvb = ga.nv[z * 16 + b];
    if (m0c >= nvb) return;
    idxb = ga.idx + (z * 16 + b) * TOK;
  }
  int n0 = blockIdx.y * 128;
  int tid = threadIdx.x;
  int w = tid >> 6, l = tid & 63;
  int wr = w >> 2, wc = w & 3;       // 2x4 wave grid; wave tile 64x32
  int lg = l >> 4, lo = l & 15;

  int cc = (l & 7) ^ (l >> 3);
  const short* pa[2];
  const short* pb[2];
#pragma unroll
  for (int i = 0; i < 2; ++i) {
    int row = (w * 2 + i) * 8 + (l >> 3);
    int rg = m0c + row;
    if (idxb != nullptr) rg = idxb[(m0c + row < nvb) ? (m0c + row) : 0];
    pa[i] = A + ((size_t)b * TOK + rg) * K + cc * 8;
    pb[i] = BT + (size_t)(n0 + row) * K + cc * 8;
  }

  f32x4 acc[4][2];
#pragma unroll
  for (int i = 0; i < 4; ++i)
#pragma unroll
    for (int j = 0; j < 2; ++j) acc[i][j] = fzero4();

  for (int k0 = 0; k0 < K; k0 += 64) {
#pragma unroll
    for (int i = 0; i < 2; ++i) {
      gl_lds16(pa[i] + k0, As + (w * 2 + i) * 512);
      gl_lds16(pb[i] + k0, Bs + (w * 2 + i) * 512);
    }
    __syncthreads();
#pragma unroll
    for (int ks = 0; ks < 2; ++ks) {
      int lc = ks * 4 + lg;
      s16x8 af[4], bfr[2];
#pragma unroll
      for (int i = 0; i < 4; ++i) {
        int ar = wr * 64 + i * 16 + lo;
        af[i] = *(const s16x8*)(As + ar * 64 + ((lc ^ (ar & 7)) * 8));
      }
#pragma unroll
      for (int j = 0; j < 2; ++j) {
        int br = wc * 32 + j * 16 + lo;
        bfr[j] = *(const s16x8*)(Bs + br * 64 + ((lc ^ (br & 7)) * 8));
      }
#pragma unroll
      for (int i = 0; i < 4; ++i)
#pragma unroll
        for (int j = 0; j < 2; ++j)
          acc[i][j] = MFMA(af[i], bfr[j], acc[i][j]);
    }
    __syncthreads();
  }

#pragma unroll
  for (int i = 0; i < 4; ++i)
#pragma unroll
    for (int j = 0; j < 2; ++j) {
      int rowc = m0c + wr * 64 + i * 16 + (lg << 2);
      int col = n0 + wc * 32 + j * 16 + lo;
      float cs = 1.f;
      if (gate != nullptr && col < 2048) cs = gate[b * DM + (col & 1023)];
      float bv = bias[col];
#pragma unroll
      for (int r = 0; r < 4; ++r) {
        if (rowc + r >= nvb) continue;
        float val = (acc[i][j][r] + bv) * cs;
        size_t orow = (size_t)b * TOK + rowc + r;
        if (outB != nullptr) outB[orow * N + col] = f2bf(val);
        else                 outF[orow * N + col] = val;
      }
    }
}

// ---------------- fused flash attention on compacted K/V/Q ----------------
struct AttnArgs {
  const short* kqv[3];
  const float* kmem[3];
  const float* vmem[3];
  const float* xin[3];
  short* xu[3];
  const int* idx;
  const int* nv;
  int kmem_bstride[3];
};

__global__ __launch_bounds__(512) void attn_kernel(AttnArgs args) {
  __shared__ short Ks[64 * 128];
  __shared__ short Vs[8 * 1032];
  __shared__ short Ps[8 * 1216];
  int bid = blockIdx.x;
  int mod = bid >> 9;
  int r9 = bid & 511;
  int x = r9 & 7, jj = r9 >> 3;
  int p = x * 16 + (jj & 15), qt = jj >> 4;
  int b = p >> 3, h = p & 7;

  int nvb = args.nv[mod * 16 + b];
  if (qt * 128 >= nvb) return;

  const short* kqv  = args.kqv[mod];
  const float* kmem = args.kmem[mod];
  const float* vmem = args.vmem[mod];
  const float* xin  = args.xin[mod];
  short* xu = args.xu[mod];
  const int* idxb = args.idx + (mod * 16 + b) * TOK;
  int kmem_bs = args.kmem_bstride[mod];

  int tid = threadIdx.x;
  int w = tid >> 6, l = tid & 63;
  int lg = l >> 4, lo = l & 15;
  size_t rowbase = (size_t)b * TOK;
  int q0 = qt * 128 + w * 16;
  const float scale = 0.08838834764831845f;
  short* Pw = Ps + w * 1216;
  int nkt = (nvb + 63) >> 6;

  s16x8 ones;
#pragma unroll
  for (int j = 0; j < 8; ++j) ones[j] = (short)0x3F80;

  int qrow = q0 + lo;
  s16x8 qf[4];
#pragma unroll
  for (int c = 0; c < 4; ++c)
    qf[c] = (qrow < nvb)
      ? *(const s16x8*)(kqv + (rowbase + qrow) * LDK + 1024 + h * 128 + c * 32 + lg * 8)
      : szero8();

  float m;
  f32x4 oacc[9];
#pragma unroll
  for (int c = 0; c < 9; ++c) oacc[c] = fzero4();

  if (kmem != nullptr) {
    const float* km = kmem + (size_t)b * kmem_bs + h * 128;
    float part = 0.f;
#pragma unroll
    for (int c = 0; c < 4; ++c)
#pragma unroll
      for (int j = 0; j < 8; ++j)
        part += bf2f(qf[c][j]) * km[c * 32 + lg * 8 + j];
    part += __shfl_xor(part, 16);
    part += __shfl_xor(part, 32);
    float sm = part * scale;
    float sm4[4], w4[4];
#pragma unroll
    for (int r = 0; r < 4; ++r) sm4[r] = __shfl(sm, lg * 4 + r);
    m = fmaxf(fmaxf(sm4[0], sm4[1]), fmaxf(sm4[2], sm4[3]));
#pragma unroll
    for (int r = 0; r < 4; ++r) w4[r] = __expf(sm4[r] - m);
#pragma unroll
    for (int c = 0; c < 8; ++c) {
      float vv = vmem[h * 128 + c * 16 + lo];
#pragma unroll
      for (int r = 0; r < 4; ++r) oacc[c][r] = w4[r] * vv;
    }
#pragma unroll
    for (int r = 0; r < 4; ++r) oacc[8][r] = w4[r];
  } else {
    m = -3.0e38f;
  }

  int c8A = 2 * w, c8B = 2 * w + 1;
  s16x8 vregA = (l < nvb)
    ? *(const s16x8*)(kqv + (rowbase + l) * LDK + 2048 + h * 128 + c8A * 8) : szero8();
  s16x8 vregB = (l < nvb)
    ? *(const s16x8*)(kqv + (rowbase + l) * LDK + 2048 + h * 128 + c8B * 8) : szero8();

#pragma unroll 1
  for (int kt = 0; kt < nkt; ++kt) {
    __syncthreads();
#pragma unroll
    for (int i = 0; i < 2; ++i) {
      int inst = w * 2 + i;
      int row = inst * 4 + lg;
      int csrc = (l & 15) ^ (row & 7);
      gl_lds16(kqv + (rowbase + kt * 64 + row) * LDK + h * 128 + csrc * 8,
               Ks + inst * 512);
    }
    {
      short* baseA = Vs + (l >> 3) * 1032 + c8A * 64 + (l & 7);
      short* baseB = Vs + (l >> 3) * 1032 + c8B * 64 + (l & 7);
#pragma unroll
      for (int j = 0; j < 8; ++j) baseA[j * 8] = vregA[j];
#pragma unroll
      for (int j = 0; j < 8; ++j) baseB[j * 8] = vregB[j];
    }
    __syncthreads();

    if (kt + 1 < nkt) {
      int row2 = (kt + 1) * 64 + l;
      vregA = (row2 < nvb)
        ? *(const s16x8*)(kqv + (rowbase + row2) * LDK + 2048 + h * 128 + c8A * 8) : szero8();
      vregB = (row2 < nvb)
        ? *(const s16x8*)(kqv + (rowbase + row2) * LDK + 2048 + h * 128 + c8B * 8) : szero8();
    }

    f32x4 s4[4];
#pragma unroll
    for (int sub = 0; sub < 4; ++sub) {
      f32x4 acc = fzero4();
      int krow = sub * 16 + lo;
#pragma unroll
      for (int cc = 0; cc < 4; ++cc) {
        s16x8 kf = *(const s16x8*)(Ks + krow * 128 + (((cc * 4 + lg) ^ (lo & 7)) * 8));
        acc = MFMA(qf[cc], kf, acc);
      }
      s4[sub] = acc;
    }

    int pos0 = kt * 64 + lo;
    float a[4][4];
    float pmax = -3.0e38f;
#pragma unroll
    for (int r = 0; r < 4; ++r) {
      a[0][r] = (pos0      < nvb) ? s4[0][r] * scale : -1e9f;
      a[1][r] = (pos0 + 16 < nvb) ? s4[1][r] * scale : -1e9f;
      a[2][r] = (pos0 + 32 < nvb) ? s4[2][r] * scale : -1e9f;
      a[3][r] = (pos0 + 48 < nvb) ? s4[3][r] * scale : -1e9f;
      pmax = fmaxf(pmax, fmaxf(fmaxf(a[0][r], a[1][r]), fmaxf(a[2][r], a[3][r])));
    }
    pmax = fmaxf(pmax, __shfl_xor(pmax, 1));
    pmax = fmaxf(pmax, __shfl_xor(pmax, 2));
    pmax = fmaxf(pmax, __shfl_xor(pmax, 4));
    pmax = fmaxf(pmax, __shfl_xor(pmax, 8));
    if (!__all(pmax - m <= 8.0f)) {
      float nm = fmaxf(m, pmax);
      float f = __expf(m - nm);
#pragma unroll
      for (int c = 0; c < 9; ++c)
#pragma unroll
        for (int r = 0; r < 4; ++r) oacc[c][r] *= f;
      m = nm;
    }

#pragma unroll
    for (int sub = 0; sub < 4; ++sub)
#pragma unroll
      for (int r = 0; r < 4; ++r)
        Pw[(lg * 4 + r) * 76 + sub * 16 + lo] = f2bf(__expf(a[sub][r] - m));

    s16x8 pf0 = *(const s16x8*)(Pw + lo * 76 + lg * 8);
    s16x8 pf1 = *(const s16x8*)(Pw + lo * 76 + 32 + lg * 8);
#pragma unroll
    for (int c = 0; c < 8; ++c) {
      s16x8 vf0 = *(const s16x8*)(Vs + lg * 1032 + (c * 16 + lo) * 8);
      s16x8 vf1 = *(const s16x8*)(Vs + (4 + lg) * 1032 + (c * 16 + lo) * 8);
      oacc[c] = MFMA(pf0, vf0, oacc[c]);
      oacc[c] = MFMA(pf1, vf1, oacc[c]);
    }
    oacc[8] = MFMA(pf0, ones, oacc[8]);
    oacc[8] = MFMA(pf1, ones, oacc[8]);
  }

  int orig[4];
#pragma unroll
  for (int r = 0; r < 4; ++r) {
    int crow = q0 + lg * 4 + r;
    orig[r] = (crow < nvb) ? idxb[crow] : -1;
  }
  float invl[4];
#pragma unroll
  for (int r = 0; r < 4; ++r) invl[r] = 1.f / oacc[8][r];
#pragma unroll
  for (int c = 0; c < 8; ++c)
#pragma unroll
    for (int r = 0; r < 4; ++r) {
      if (orig[r] < 0) continue;
      size_t row = rowbase + orig[r];
      int col = h * 128 + c * 16 + lo;
      float val = oacc[c][r] * invl[r] + xin[row * DM + col];
      xu[row * DM + col] = f2bf(val);
    }
}

// ---------------- masked rows: xu = x + uniform avg of valid V (+mem) ----------------
struct UniArgs {
  const short* kqv[3]; const float* mask[3]; const float* mem[3];
  const float* xin[3]; short* xu[3]; const int* nv;
};
__global__ __launch_bounds__(1024) void uniform_fill_kernel(UniArgs a) {
  __shared__ float part[8][1024];
  int b = blockIdx.x, mod = blockIdx.y;
  int nvb = a.nv[mod * 16 + b];
  const short* kv = a.kqv[mod];
  int tid = threadIdx.x;
  int g = tid >> 7;
  int dd = tid & 127;

  f32x4 p0 = fzero4(), p1 = fzero4();
#pragma unroll 2
  for (int r = g; r < nvb; r += 8) {
    s16x8 vv = *(const s16x8*)(kv + ((size_t)b * TOK + r) * LDK + 2048 + dd * 8);
#pragma unroll
    for (int j = 0; j < 4; ++j) { p0[j] += bf2f(vv[j]); p1[j] += bf2f(vv[4 + j]); }
  }
  *(f32x4*)&part[g][dd * 8] = p0;
  *(f32x4*)&part[g][dd * 8 + 4] = p1;
  __syncthreads();
  {
    float s = 0.f;
#pragma unroll
    for (int gg = 0; gg < 8; ++gg) s += part[gg][tid];
    float denom = (float)nvb;
    if (a.mem[mod] != nullptr) { s += a.mem[mod][tid]; denom += 1.f; }
    __syncthreads();
    part[0][tid] = s / denom;
  }
  __syncthreads();
  float avg[8];
#pragma unroll
  for (int j = 0; j < 8; ++j) avg[j] = part[0][dd * 8 + j];

  const float* mk = a.mask[mod] + b * TOK;
  const float* x = a.xin[mod];
  short* xu = a.xu[mod];
#pragma unroll 1
  for (int rb = 0; rb < TOK; rb += 8) {
    int r = rb + g;
    if (mk[r] != 0.f) continue;
    size_t base = ((size_t)b * TOK + r) * DM + dd * 8;
    float4 x0 = *(const float4*)(x + base);
    float4 x1 = *(const float4*)(x + base + 4);
    s16x8 o;
    o[0] = f2bf(x0.x + avg[0]); o[1] = f2bf(x0.y + avg[1]);
    o[2] = f2bf(x0.z + avg[2]); o[3] = f2bf(x0.w + avg[3]);
    o[4] = f2bf(x1.x + avg[4]); o[5] = f2bf(x1.y + avg[5]);
    o[6] = f2bf(x1.z + avg[6]); o[7] = f2bf(x1.w + avg[7]);
    *(s16x8*)(xu + base) = o;
  }
}

// ---------------- launcher ----------------
extern "C" void kernel_launch(void* const* d_in, const int* in_sizes, int n_in,
                              void* d_out, int out_size, void* d_ws, size_t ws_size,
                              hipStream_t stream) {
  const float* v      = (const float*)d_in[0];
  const float* q      = (const float*)d_in[1];
  const float* c      = (const float*)d_in[2];
  const float* v_mask = (const float*)d_in[3];
  const float* q_mask = (const float*)d_in[4];
  const float* c_mask = (const float*)d_in[5];
  const float* v4q_w  = (const float*)d_in[6];
  const float* v4q_b  = (const float*)d_in[7];
  const float* q4v_w  = (const float*)d_in[8];
  const float* q4v_b  = (const float*)d_in[9];
  const float* v_lin_w = (const float*)d_in[10];
  const float* v_lin_b = (const float*)d_in[11];
  const float* q_lin_w = (const float*)d_in[12];
  const float* q_lin_b = (const float*)d_in[13];
  const float* c_lin_w = (const float*)d_in[14];
  const float* c_lin_b = (const float*)d_in[15];
  const float* m_v_k  = (const float*)d_in[16];
  const float* m_v_v  = (const float*)d_in[17];
  const float* m_c_k  = (const float*)d_in[18];
  const float* m_c_v  = (const float*)d_in[19];
  const float* v_out_w = (const float*)d_in[20];
  const float* v_out_b = (const float*)d_in[21];
  const float* q_out_w = (const float*)d_in[22];
  const float* q_out_b = (const float*)d_in[23];
  const float* c_out_w = (const float*)d_in[24];
  const float* c_out_b = (const float*)d_in[25];

  const size_t MB = 1024ull * 1024ull;
  char* ws = (char*)d_ws;
  short* xbf_v = (short*)(ws + 0 * MB);      // 16MB each; reused as xu after trans GEMMs
  short* xbf_q = (short*)(ws + 16 * MB);
  short* xbf_c = (short*)(ws + 32 * MB);
  short* wt_lin_v = (short*)(ws + 48 * MB);
  short* wt_lin_q = (short*)(ws + 54 * MB);
  short* wt_lin_c = (short*)(ws + 60 * MB);
  short* wt_out_v = (short*)(ws + 66 * MB);
  short* wt_out_q = (short*)(ws + 68 * MB);
  short* wt_out_c = (short*)(ws + 70 * MB);
  short* kqv_v = (short*)(ws + 72 * MB);     // 48MB each
  short* kqv_q = (short*)(ws + 120 * MB);
  short* kqv_c = (short*)(ws + 168 * MB);
  float* vmean  = (float*)(ws + 216 * MB);
  float* qmean  = vmean + 16 * 1024;
  float* gate_q = qmean + 16 * 1024;
  float* gate_v = gate_q + 16 * 1024;
  float* kmem_v = gate_v + 16 * 1024;
  float* kmem_c = kmem_v + 16 * 1024;
  int* idxbuf = (int*)(ws + 217 * MB);
  int* nvbuf  = (int*)(ws + 218 * MB);

  CompArgs cpa;
  cpa.mask[0] = v_mask; cpa.mask[1] = q_mask; cpa.mask[2] = c_mask;
  cpa.idx = idxbuf; cpa.nv = nvbuf;
  compact_kernel<<<dim3(16, 3), 64, 0, stream>>>(cpa);

  CastArgs ca;
  ca.x[0] = v; ca.x[1] = q; ca.x[2] = c;
  ca.xb[0] = xbf_v; ca.xb[1] = xbf_q; ca.xb[2] = xbf_c;
  ca.mask[0] = v_mask; ca.mask[1] = q_mask; ca.mask[2] = c_mask;
  cast_relu_kernel<<<dim3(4096, 3), 256, 0, stream>>>(ca);
  mean_kernel<<<dim3(4, 16, 2), 1024, 0, stream>>>(v, q, v_mask, q_mask, vmean, qmean);

  TransArgs tl;
  tl.w[0] = v_lin_w; tl.w[1] = q_lin_w; tl.w[2] = c_lin_w;
  tl.wt[0] = wt_lin_v; tl.wt[1] = wt_lin_q; tl.wt[2] = wt_lin_c;
  transpose_cast_kernel<<<dim3(96, 32, 3), dim3(32, 8), 0, stream>>>(tl, 1024, 3072);
  TransArgs to;
  to.w[0] = v_out_w; to.w[1] = q_out_w; to.w[2] = c_out_w;
  to.wt[0] = wt_out_v; to.wt[1] = wt_out_q; to.wt[2] = wt_out_c;
  transpose_cast_kernel<<<dim3(32, 32, 3), dim3(32, 8), 0, stream>>>(to, 1024, 1024);

  gate_kernel<<<dim3(4, 16, 2), 1024, 0, stream>>>(vmean, qmean, v4q_w, v4q_b, q4v_w, q4v_b,
                                                   gate_q, gate_v);
  kmem_kernel<<<17, 1024, 0, stream>>>(m_v_k, m_c_k, gate_v, kmem_v, kmem_c);

  GemmArgs gt;
  gt.A[0] = xbf_v; gt.A[1] = xbf_q; gt.A[2] = xbf_c;
  gt.BT[0] = wt_lin_v; gt.BT[1] = wt_lin_q; gt.BT[2] = wt_lin_c;
  gt.bias[0] = v_lin_b; gt.bias[1] = q_lin_b; gt.bias[2] = c_lin_b;
  gt.gate[0] = gate_v; gt.gate[1] = gate_q; gt.gate[2] = nullptr;
  gt.outB[0] = kqv_v; gt.outB[1] = kqv_q; gt.outB[2] = kqv_c;
  gt.outF[0] = nullptr; gt.outF[1] = nullptr; gt.outF[2] = nullptr;
  gt.idx = idxbuf; gt.nv = nvbuf;
  gemm_kernel<<<dim3(64, 24, 3), 512, 0, stream>>>(gt, 3072, 1024);

  AttnArgs aa;
  aa.kqv[0] = kqv_v; aa.kqv[1] = kqv_q; aa.kqv[2] = kqv_c;
  aa.kmem[0] = kmem_v; aa.kmem[1] = nullptr; aa.kmem[2] = kmem_c;
  aa.vmem[0] = m_v_v; aa.vmem[1] = nullptr; aa.vmem[2] = m_c_v;
  aa.xin[0] = v; aa.xin[1] = q; aa.xin[2] = c;
  aa.xu[0] = xbf_v; aa.xu[1] = xbf_q; aa.xu[2] = xbf_c;
  aa.idx = idxbuf; aa.nv = nvbuf;
  aa.kmem_bstride[0] = 1024; aa.kmem_bstride[1] = 0; aa.kmem_bstride[2] = 0;
  attn_kernel<<<1536, 512, 0, stream>>>(aa);

  UniArgs ua;
  ua.kqv[0] = kqv_v; ua.kqv[1] = kqv_q; ua.kqv[2] = kqv_c;
  ua.mask[0] = v_mask; ua.mask[1] = q_mask; ua.mask[2] = c_mask;
  ua.mem[0] = m_v_v; ua.mem[1] = nullptr; ua.mem[2] = m_c_v;
  ua.xin[0] = v; ua.xin[1] = q; ua.xin[2] = c;
  ua.xu[0] = xbf_v; ua.xu[1] = xbf_q; ua.xu[2] = xbf_c;
  ua.nv = nvbuf;
  uniform_fill_kernel<<<dim3(16, 3), 1024, 0, stream>>>(ua);

  float* outp = (float*)d_out;
  GemmArgs go;
  go.A[0] = xbf_v; go.A[1] = xbf_q; go.A[2] = xbf_c;
  go.BT[0] = wt_out_v; go.BT[1] = wt_out_q; go.BT[2] = wt_out_c;
  go.bias[0] = v_out_b; go.bias[1] = q_out_b; go.bias[2] = c_out_b;
  go.gate[0] = nullptr; go.gate[1] = nullptr; go.gate[2] = nullptr;
  go.outB[0] = nullptr; go.outB[1] = nullptr; go.outB[2] = nullptr;
  go.outF[0] = outp; go.outF[1] = outp + 8388608; go.outF[2] = outp + 16777216;
  go.idx = nullptr; go.nv = nullptr;
  gemm_kernel<<<dim3(64, 8, 3), 512, 0, stream>>>(go, 1024, 1024);
}